// Round 17
// baseline (232.676 us; speedup 1.0000x reference)
//
#include <hip/hip_runtime.h>
#include <hip/hip_bf16.h>
#include <math.h>

typedef _Float16 f16;
typedef _Float16 h8 __attribute__((ext_vector_type(8)));
typedef _Float16 h4 __attribute__((ext_vector_type(4)));
typedef float    f4 __attribute__((ext_vector_type(4)));

__device__ __forceinline__ float elu_f(float v) { return v > 0.f ? v : __expf(v) - 1.f; }
__device__ __forceinline__ float sigmoid_f(float v) { return 1.f / (1.f + __expf(-v)); }

// ===== combined prep: enc transpose (blocks 0..127) + fragment-ordered weights =====
struct PrepDesc { const float* src; unsigned dstOff; int OC; int IC; int tr; };
struct P8 { PrepDesc d[8]; };

__global__ void prep_all_k(P8 p, f16* __restrict__ wp,
                           const float* __restrict__ enc, f16* __restrict__ enc_cl) {
    __shared__ float ts[32][257];
    if (blockIdx.x < 128) {
        const int b = blockIdx.x >> 4, cg = blockIdx.x & 15;
        const int tid = threadIdx.x;
        #pragma unroll
        for (int i = 0; i < 32; ++i)
            ts[i][tid] = enc[((size_t)(b * 512 + cg * 32 + i)) * 256 + tid];
        __syncthreads();
        #pragma unroll
        for (int k = 0; k < 4; ++k) {
            h8 v;
            #pragma unroll
            for (int q = 0; q < 8; ++q) v[q] = (f16)ts[k * 8 + q][tid];
            *(h8*)(enc_cl + ((size_t)(b * 256 + tid)) * 512 + cg * 32 + k * 8) = v;
        }
        return;
    }
    unsigned idx = (blockIdx.x - 128) * 256u + threadIdx.x;
    for (int s = 0; s < 8; ++s) {
        const int IC = p.d[s].IC, OC = p.d[s].OC;
        const unsigned cnt = (unsigned)(OC * 9 * IC);
        if (idx < cnt) {
            const int nicc = IC >> 5;
            const int j    = idx & 7;
            const int lane = (idx >> 3) & 63;
            const int mt   = (idx >> 9) & 1;
            unsigned r = idx >> 10;
            const int tap = r % 9;  r /= 9;
            const int icchunk = r % nicc;
            const int ocg     = r / nicc;
            const int oc = ocg * 32 + mt * 16 + (lane & 15);
            const int ic = icchunk * 32 + (lane >> 4) * 8 + j;
            const float v = p.d[s].tr ? p.d[s].src[((size_t)ic * OC + oc) * 9 + tap]
                                      : p.d[s].src[((size_t)oc * IC + ic) * 9 + tap];
            wp[p.d[s].dstOff + idx] = (f16)v;
            return;
        }
        idx -= cnt;
    }
}

// ===== fused staging element: sum SKS partials + producer bias + ELU =====
template<int SKS>
__device__ __forceinline__ h8 stage_elem(const f16* __restrict__ in, size_t off,
                                         size_t srcTot, const float* __restrict__ sbias,
                                         int ch0) {
    if constexpr (SKS == 1) {
        return *(const h8*)(in + off);
    } else {
        float s[8];
        const h8 t0 = *(const h8*)(in + off);
        #pragma unroll
        for (int j = 0; j < 8; ++j) s[j] = (float)t0[j];
        #pragma unroll
        for (int k = 1; k < SKS; ++k) {
            const h8 tk = *(const h8*)(in + (size_t)k * srcTot + off);
            #pragma unroll
            for (int j = 0; j < 8; ++j) s[j] += (float)tk[j];
        }
        const float4 b0 = *(const float4*)(sbias + ch0);
        const float4 b1 = *(const float4*)(sbias + ch0 + 4);
        h8 v;
        v[0] = (f16)elu_f(s[0] + b0.x); v[1] = (f16)elu_f(s[1] + b0.y);
        v[2] = (f16)elu_f(s[2] + b0.z); v[3] = (f16)elu_f(s[3] + b0.w);
        v[4] = (f16)elu_f(s[4] + b1.x); v[5] = (f16)elu_f(s[5] + b1.y);
        v[6] = (f16)elu_f(s[6] + b1.z); v[7] = (f16)elu_f(s[7] + b1.w);
        return v;
    }
}

// ================= Conv2d(k3,p1)+ELU via MFMA, channel-last f16 ====================
template<int C, int H, int W, int HT, int WT, int NWN, int KS, int SKS>
__launch_bounds__(256, 2)
__global__ void conv3_mfma(const f16* __restrict__ in, const f16* __restrict__ wp,
                           const float* __restrict__ bias, const float* __restrict__ sbias,
                           size_t srcTot, f16* __restrict__ out, f16* __restrict__ pout) {
    constexpr int NWR = 4 / NWN;
    constexpr int RH  = HT / NWR;
    constexpr int PIXR = WT + 2;
    constexpr int ROWS = HT + 2;
    constexpr int XB = ROWS * PIXR * 80;
    constexpr int NICC = C / 32;
    constexpr int XTILES = W / WT;
    constexpr int NLD = ROWS * PIXR * 4;
    constexpr int NIT = (NLD + 255) / 256;
    constexpr int CPB = C / KS / 32;
    __shared__ __align__(16) char xlds[XB];

    const int tid = threadIdx.x;
    const int wid = tid >> 6, lane = tid & 63;
    const int ln15 = lane & 15, lg = lane >> 4;
    const int ni = wid % NWN, ri = wid / NWN;
    const int bz = blockIdx.z;
    const int bb = bz / (C / 32), ocg = bz % (C / 32);
    const int oc0 = ocg * 32;
    const int bx = blockIdx.x;
    const int xt = bx % XTILES, ks = bx / XTILES;
    const int h0 = blockIdx.y * HT, w0 = xt * WT;
    const int colb = ni * 16 + ln15;

    f4 acc[RH][2] = {};

    auto compute_chunk = [&](int icc) {
        const f16* wbl = wp + ((size_t)(ocg * NICC + (icc >> 5)) * 18) * 512 + lane * 8;
        #pragma unroll
        for (int dw = 0; dw < 3; ++dw) {
            h8 afd[3][2];
            #pragma unroll
            for (int dh = 0; dh < 3; ++dh)
                #pragma unroll
                for (int mt = 0; mt < 2; ++mt)
                    afd[dh][mt] = *(const h8*)(wbl + ((dh * 3 + dw) * 2 + mt) * 512);
            h8 bfv[RH + 2];
            #pragma unroll
            for (int q = 0; q < RH + 2; ++q)
                bfv[q] = *(const h8*)(xlds + ((ri * RH + q) * PIXR + colb + dw) * 80 + lg * 16);
            #pragma unroll
            for (int r = 0; r < RH; ++r) {
                #pragma unroll
                for (int dh = 0; dh < 3; ++dh) {
                    acc[r][0] = __builtin_amdgcn_mfma_f32_16x16x32_f16(afd[dh][0], bfv[r + dh], acc[r][0], 0, 0, 0);
                    acc[r][1] = __builtin_amdgcn_mfma_f32_16x16x32_f16(afd[dh][1], bfv[r + dh], acc[r][1], 0, 0, 0);
                }
            }
        }
    };

    if constexpr (SKS == 1 && CPB > 1) {
        h8 pre[NIT];
        const int icc0 = ks * (C / KS);
        auto do_loads = [&](int icc) {
            #pragma unroll
            for (int i = 0; i < NIT; ++i) {
                const int t = tid + i * 256;
                if (t < NLD) {
                    const int g = t & 3, pix = t >> 2;
                    const int rr = pix / PIXR, ww = pix - rr * PIXR;
                    const int gh = h0 - 1 + rr, gw = w0 - 1 + ww;
                    h8 v = {};
                    if (gh >= 0 && gh < H && gw >= 0 && gw < W)
                        v = *(const h8*)(in + (((size_t)bb * H + gh) * W + gw) * C + icc + g * 8);
                    pre[i] = v;
                }
            }
        };
        do_loads(icc0);
        for (int ci = 0; ci < CPB; ++ci) {
            __syncthreads();
            #pragma unroll
            for (int i = 0; i < NIT; ++i) {
                const int t = tid + i * 256;
                if (t < NLD) {
                    const int g = t & 3, pix = t >> 2;
                    *(h8*)(xlds + pix * 80 + g * 16) = pre[i];
                }
            }
            __syncthreads();
            if (ci + 1 < CPB) do_loads(icc0 + (ci + 1) * 32);
            compute_chunk(icc0 + ci * 32);
        }
    } else {
        for (int icc = ks * (C / KS); icc < (ks + 1) * (C / KS); icc += 32) {
            __syncthreads();
            for (int t = tid; t < NLD; t += 256) {
                const int g = t & 3, pix = t >> 2;
                const int rr = pix / PIXR, ww = pix - rr * PIXR;
                const int gh = h0 - 1 + rr, gw = w0 - 1 + ww;
                h8 v = {};
                if (gh >= 0 && gh < H && gw >= 0 && gw < W) {
                    const size_t off = (((size_t)bb * H + gh) * W + gw) * C + icc + g * 8;
                    v = stage_elem<SKS>(in, off, srcTot, sbias, icc + g * 8);
                }
                *(h8*)(xlds + pix * 80 + g * 16) = v;
            }
            __syncthreads();
            compute_chunk(icc);
        }
    }

    #pragma unroll
    for (int r = 0; r < RH; ++r) {
        const int oh = h0 + ri * RH + r;
        const int ow = w0 + colb;
        #pragma unroll
        for (int mt = 0; mt < 2; ++mt) {
            const int ocl = mt * 16 + lg * 4;
            const f4 v = acc[r][mt];
            if constexpr (KS > 1) {
                const size_t TOT = (size_t)8 * H * W * C;
                h4 hv = {(f16)v.x, (f16)v.y, (f16)v.z, (f16)v.w};
                *(h4*)(pout + (size_t)ks * TOT +
                       (((size_t)bb * H + oh) * W + ow) * C + oc0 + ocl) = hv;
            } else {
                const float4 b4 = *(const float4*)(bias + oc0 + ocl);
                h4 hv = {(f16)elu_f(v.x + b4.x), (f16)elu_f(v.y + b4.y),
                         (f16)elu_f(v.z + b4.z), (f16)elu_f(v.w + b4.w)};
                *(h4*)(out + (((size_t)bb * H + oh) * W + ow) * C + oc0 + ocl) = hv;
            }
        }
    }
}

// ================= ConvTranspose2d(k3,s2,p1,op1)+ELU via MFMA ======================
template<int IC, int OC, int Hi, int Wi, int KS, int SKS>
__launch_bounds__(256, 2)
__global__ void convt_mfma(const f16* __restrict__ in, const f16* __restrict__ wp,
                           const float* __restrict__ bias, const float* __restrict__ sbias,
                           size_t srcTot, f16* __restrict__ out, f16* __restrict__ pout) {
    constexpr int HT = 4, WT = 16;
    constexpr int PIXR = WT + 1;
    constexpr int ROWS = HT + 1;
    constexpr int XB = ROWS * PIXR * 80;
    constexpr int NICC = IC / 32;
    constexpr int XTILES = Wi / WT;
    constexpr int NLD = ROWS * PIXR * 4;
    constexpr int NIT = (NLD + 255) / 256;
    constexpr int CPB = IC / KS / 32;
    __shared__ __align__(16) char xlds[XB];

    const int tid = threadIdx.x;
    const int wid = tid >> 6, lane = tid & 63;
    const int ln15 = lane & 15, lg = lane >> 4;
    const int iloc = wid;
    const int bz = blockIdx.z;
    const int bb = bz / (OC / 32), ocg = bz % (OC / 32);
    const int oc0 = ocg * 32;
    const int bx = blockIdx.x;
    const int xt = bx % XTILES, ks = bx / XTILES;
    const int i0 = blockIdx.y * HT, j0 = xt * WT;

    f4 acc[4][2] = {};

    auto compute_chunk = [&](int icc) {
        const f16* wbl = wp + ((size_t)(ocg * NICC + (icc >> 5)) * 18) * 512 + lane * 8;
        h8 af[9][2];
        #pragma unroll
        for (int tap = 0; tap < 9; ++tap)
            #pragma unroll
            for (int mt = 0; mt < 2; ++mt)
                af[tap][mt] = *(const h8*)(wbl + (tap * 2 + mt) * 512);

        h8 bf[2][2];
        #pragma unroll
        for (int a = 0; a < 2; ++a)
            #pragma unroll
            for (int b = 0; b < 2; ++b)
                bf[a][b] = *(const h8*)(xlds + ((iloc + a) * PIXR + ln15 + b) * 80 + lg * 16);

        #pragma unroll
        for (int p = 0; p < 4; ++p) {
            const int di = p >> 1, dj = p & 1;
            #pragma unroll
            for (int a = 0; a < 2; ++a) {
                if (a > di) continue;
                const int kh = 1 + di - 2 * a;
                #pragma unroll
                for (int b = 0; b < 2; ++b) {
                    if (b > dj) continue;
                    const int kw = 1 + dj - 2 * b;
                    const int tap = kh * 3 + kw;
                    acc[p][0] = __builtin_amdgcn_mfma_f32_16x16x32_f16(af[tap][0], bf[a][b], acc[p][0], 0, 0, 0);
                    acc[p][1] = __builtin_amdgcn_mfma_f32_16x16x32_f16(af[tap][1], bf[a][b], acc[p][1], 0, 0, 0);
                }
            }
        }
    };

    if constexpr (SKS == 1 && CPB > 1) {
        h8 pre[NIT];
        const int icc0 = ks * (IC / KS);
        auto do_loads = [&](int icc) {
            #pragma unroll
            for (int i = 0; i < NIT; ++i) {
                const int t = tid + i * 256;
                if (t < NLD) {
                    const int g = t & 3, pix = t >> 2;
                    const int rr = pix / PIXR, ww = pix - rr * PIXR;
                    const int gh = i0 + rr, gw = j0 + ww;
                    h8 v = {};
                    if (gh < Hi && gw < Wi)
                        v = *(const h8*)(in + (((size_t)bb * Hi + gh) * Wi + gw) * IC + icc + g * 8);
                    pre[i] = v;
                }
            }
        };
        do_loads(icc0);
        for (int ci = 0; ci < CPB; ++ci) {
            __syncthreads();
            #pragma unroll
            for (int i = 0; i < NIT; ++i) {
                const int t = tid + i * 256;
                if (t < NLD) {
                    const int g = t & 3, pix = t >> 2;
                    *(h8*)(xlds + pix * 80 + g * 16) = pre[i];
                }
            }
            __syncthreads();
            if (ci + 1 < CPB) do_loads(icc0 + (ci + 1) * 32);
            compute_chunk(icc0 + ci * 32);
        }
    } else {
        for (int icc = ks * (IC / KS); icc < (ks + 1) * (IC / KS); icc += 32) {
            __syncthreads();
            for (int t = tid; t < NLD; t += 256) {
                const int g = t & 3, pix = t >> 2;
                const int rr = pix / PIXR, ww = pix - rr * PIXR;
                const int gh = i0 + rr, gw = j0 + ww;
                h8 v = {};
                if (gh < Hi && gw < Wi) {
                    const size_t off = (((size_t)bb * Hi + gh) * Wi + gw) * IC + icc + g * 8;
                    v = stage_elem<SKS>(in, off, srcTot, sbias, icc + g * 8);
                }
                *(h8*)(xlds + pix * 80 + g * 16) = v;
            }
            __syncthreads();
            compute_chunk(icc);
        }
    }

    #pragma unroll
    for (int p = 0; p < 4; ++p) {
        const int orow = 2 * (i0 + iloc) + (p >> 1);
        const int ocol = 2 * (j0 + ln15) + (p & 1);
        #pragma unroll
        for (int mt = 0; mt < 2; ++mt) {
            const int ocl = mt * 16 + lg * 4;
            const f4 v = acc[p][mt];
            if constexpr (KS > 1) {
                const size_t TOT = (size_t)8 * (2 * Hi) * (2 * Wi) * OC;
                h4 hv = {(f16)v.x, (f16)v.y, (f16)v.z, (f16)v.w};
                *(h4*)(pout + (size_t)ks * TOT +
                       (((size_t)bb * (2 * Hi) + orow) * (2 * Wi) + ocol) * OC + oc0 + ocl) = hv;
            } else {
                const float4 b4 = *(const float4*)(bias + oc0 + ocl);
                h4 hv = {(f16)elu_f(v.x + b4.x), (f16)elu_f(v.y + b4.y),
                         (f16)elu_f(v.z + b4.z), (f16)elu_f(v.w + b4.w)};
                *(h4*)(out + (((size_t)bb * (2 * Hi) + orow) * (2 * Wi) + ocol) * OC + oc0 + ocl) = hv;
            }
        }
    }
}

// ======== L7 conv3(32ch,256²) + fused Gram partials, HT=2 (4096 blocks) ========
// Per-wave tile: 2 rows x 16 cols = 32 px, all 32 ch. Gram = single k=32 MFMA step.
// LDS 21120 B -> 7 blocks/CU cap. Per-wave scratch WSB=4352 aliases staging region:
// x3w [32][40] f16 (2560 B); pl (4096 B, aliases x3w after this wave's reads); sl +4096.
__launch_bounds__(256, 2)
__global__ void conv3_gram_k(const f16* __restrict__ in, const f16* __restrict__ wp,
                             const float* __restrict__ bias, const float* __restrict__ sem,
                             f16* __restrict__ out, float* __restrict__ part,
                             float* __restrict__ sums) {
    constexpr int C = 32, H = 256, W = 256, HT = 2, WT = 64;
    constexpr int PIXR = WT + 2;               // 66
    constexpr int ROWS = HT + 2;               // 4
    constexpr int XB = ROWS * PIXR * 80;       // 21120
    constexpr int WSB = 4352;
    __shared__ __align__(16) char lds[XB];
    char* xlds = lds;

    const int tid = threadIdx.x;
    const int wid = tid >> 6, lane = tid & 63;
    const int ln15 = lane & 15, lg = lane >> 4;
    const int ni = wid;
    const int bb = blockIdx.z;
    const int h0 = blockIdx.y * HT, w0 = blockIdx.x * WT;
    const int colb = ni * 16 + ln15;

    // ---- conv input staging ----
    for (int t = tid; t < ROWS * PIXR * 4; t += 256) {
        const int g = t & 3, pix = t >> 2;
        const int rr = pix / PIXR, ww = pix - rr * PIXR;
        const int gh = h0 - 1 + rr, gw = w0 - 1 + ww;
        h8 v = {};
        if (gh >= 0 && gh < H && gw >= 0 && gw < W)
            v = *(const h8*)(in + (((size_t)bb * H + gh) * W + gw) * C + g * 8);
        *(h8*)(xlds + pix * 80 + g * 16) = v;
    }

    // ---- prefetch sem for this wave's 2x16 px tile (k = 32 px) ----
    const int d = ln15, kg = lg;
    const size_t N = 65536;
    const float* sbase = sem + ((size_t)bb * 32 + d) * N;
    const int p0 = kg * 8;
    const int r0 = p0 >> 4, c0 = p0 & 15;
    const size_t soff = (size_t)(h0 + r0) * 256 + w0 + wid * 16 + c0;
    float4 semr[4];
    semr[0] = *(const float4*)(sbase + soff);
    semr[1] = *(const float4*)(sbase + soff + 4);
    semr[2] = *(const float4*)(sbase + 16 * N + soff);
    semr[3] = *(const float4*)(sbase + 16 * N + soff + 4);
    __syncthreads();

    // ---- conv: single K-chunk (C=32), 2 output rows per wave ----
    f4 acc[2][2] = {};
    const f16* wbl = wp + lane * 8;
    #pragma unroll
    for (int dw = 0; dw < 3; ++dw) {
        h8 afd[3][2];
        #pragma unroll
        for (int dh = 0; dh < 3; ++dh)
            #pragma unroll
            for (int mt = 0; mt < 2; ++mt)
                afd[dh][mt] = *(const h8*)(wbl + ((dh * 3 + dw) * 2 + mt) * 512);
        h8 bfv[4];
        #pragma unroll
        for (int q = 0; q < 4; ++q)
            bfv[q] = *(const h8*)(xlds + (q * PIXR + colb + dw) * 80 + lg * 16);
        #pragma unroll
        for (int r = 0; r < 2; ++r) {
            #pragma unroll
            for (int dh = 0; dh < 3; ++dh) {
                acc[r][0] = __builtin_amdgcn_mfma_f32_16x16x32_f16(afd[dh][0], bfv[r + dh], acc[r][0], 0, 0, 0);
                acc[r][1] = __builtin_amdgcn_mfma_f32_16x16x32_f16(afd[dh][1], bfv[r + dh], acc[r][1], 0, 0, 0);
            }
        }
    }
    __syncthreads();   // all waves done reading xlds -> safe to alias per-wave scratch

    // ---- epilogue: bias+ELU -> global x3cl + wave-private x3w[32ch][40] ----
    f16* x3w = (f16*)(lds + wid * WSB);
    #pragma unroll
    for (int r = 0; r < 2; ++r) {
        const int oh = h0 + r, ow = w0 + colb;
        const int px = r * 16 + ln15;
        #pragma unroll
        for (int mt = 0; mt < 2; ++mt) {
            const int ocl = mt * 16 + lg * 4;
            const float4 b4 = *(const float4*)(bias + ocl);
            const f4 v = acc[r][mt];
            h4 hv = {(f16)elu_f(v.x + b4.x), (f16)elu_f(v.y + b4.y),
                     (f16)elu_f(v.z + b4.z), (f16)elu_f(v.w + b4.w)};
            *(h4*)(out + (((size_t)bb * H + oh) * W + ow) * C + ocl) = hv;
            x3w[(ocl + 0) * 40 + px] = hv[0];
            x3w[(ocl + 1) * 40 + px] = hv[1];
            x3w[(ocl + 2) * 40 + px] = hv[2];
            x3w[(ocl + 3) * 40 + px] = hv[3];
        }
    }
    // no barrier: x3w wave-private, per-wave LDS in-order + MFMA data dependency

    // ---- gram over the wave's 32-px tile, single k-step; sem from registers ----
    const h8 a0 = *(const h8*)(x3w + d * 40 + p0);
    const h8 a1 = *(const h8*)(x3w + (16 + d) * 40 + p0);
    const h8 b0 = {(f16)semr[0].x, (f16)semr[0].y, (f16)semr[0].z, (f16)semr[0].w,
                   (f16)semr[1].x, (f16)semr[1].y, (f16)semr[1].z, (f16)semr[1].w};
    const h8 b1 = {(f16)semr[2].x, (f16)semr[2].y, (f16)semr[2].z, (f16)semr[2].w,
                   (f16)semr[3].x, (f16)semr[3].y, (f16)semr[3].z, (f16)semr[3].w};
    f4 g00 = {}, g01 = {}, g10 = {}, g11 = {};
    g00 = __builtin_amdgcn_mfma_f32_16x16x32_f16(a0, b0, g00, 0, 0, 0);
    g01 = __builtin_amdgcn_mfma_f32_16x16x32_f16(a0, b1, g01, 0, 0, 0);
    g10 = __builtin_amdgcn_mfma_f32_16x16x32_f16(a1, b0, g10, 0, 0, 0);
    g11 = __builtin_amdgcn_mfma_f32_16x16x32_f16(a1, b1, g11, 0, 0, 0);

    float sx0 = 0.f, sx1 = 0.f, ss0 = 0.f, ss1 = 0.f;
    #pragma unroll
    for (int q = 0; q < 8; ++q) { sx0 += (float)a0[q]; sx1 += (float)a1[q]; }
    ss0 = (semr[0].x + semr[0].y + semr[0].z + semr[0].w) +
          (semr[1].x + semr[1].y + semr[1].z + semr[1].w);
    ss1 = (semr[2].x + semr[2].y + semr[2].z + semr[2].w) +
          (semr[3].x + semr[3].y + semr[3].z + semr[3].w);

    sx0 += __shfl_xor(sx0, 16); sx0 += __shfl_xor(sx0, 32);
    sx1 += __shfl_xor(sx1, 16); sx1 += __shfl_xor(sx1, 32);
    ss0 += __shfl_xor(ss0, 16); ss0 += __shfl_xor(ss0, 32);
    ss1 += __shfl_xor(ss1, 16); ss1 += __shfl_xor(ss1, 32);

    // ---- per-wave partial store (aliases own x3w region; dependency-ordered) ----
    float* plw = (float*)(lds + wid * WSB);
    float* slw = (float*)(lds + wid * WSB + 4096);
    #pragma unroll
    for (int reg = 0; reg < 4; ++reg) {
        const int c0r = 4 * kg + reg;
        plw[c0r * 32 + d]             = g00[reg];
        plw[c0r * 32 + 16 + d]        = g01[reg];
        plw[(16 + c0r) * 32 + d]      = g10[reg];
        plw[(16 + c0r) * 32 + 16 + d] = g11[reg];
    }
    if (lane < 16) {
        slw[d]      = sx0;
        slw[16 + d] = sx1;
        slw[32 + d] = ss0;
        slw[48 + d] = ss1;
    }
    __syncthreads();

    // ---- cross-wave reduce + global write ----
    const float* pl0 = (const float*)(lds + 0 * WSB);
    const float* pl1 = (const float*)(lds + 1 * WSB);
    const float* pl2 = (const float*)(lds + 2 * WSB);
    const float* pl3 = (const float*)(lds + 3 * WSB);
    const int chunk = blockIdx.y * 4 + blockIdx.x;       // 0..511
    float* pb = part + ((size_t)bb * 512 + chunk) * 1024;
    for (int t = tid; t < 1024; t += 256)
        pb[t] = pl0[t] + pl1[t] + pl2[t] + pl3[t];
    if (tid < 64) {
        const float* s0 = (const float*)(lds + 0 * WSB + 4096);
        const float* s1 = (const float*)(lds + 1 * WSB + 4096);
        const float* s2 = (const float*)(lds + 2 * WSB + 4096);
        const float* s3 = (const float*)(lds + 3 * WSB + 4096);
        sums[((size_t)bb * 512 + chunk) * 64 + tid] = s0[tid] + s1[tid] + s2[tid] + s3[tid];
    }
}

// ================= two-level reduce: 512 partials -> 8 ============================
__launch_bounds__(256)
__global__ void gram_reduce_k(const float* __restrict__ part, const float* __restrict__ sums,
                              float* __restrict__ part2, float* __restrict__ sums2) {
    const int b = blockIdx.y, g = blockIdx.x;  // 8 x 8
    const int tid = threadIdx.x;
    const int i4 = tid * 4;
    f4 a = {};
    #pragma unroll 4
    for (int ch = 0; ch < 64; ++ch) {
        const f4 v = *(const f4*)(part + ((size_t)b * 512 + g * 64 + ch) * 1024 + i4);
        a.x += v.x; a.y += v.y; a.z += v.z; a.w += v.w;
    }
    *(f4*)(part2 + ((size_t)b * 8 + g) * 1024 + i4) = a;
    if (tid < 64) {
        float s = 0.f;
        #pragma unroll 4
        for (int ch = 0; ch < 64; ++ch) s += sums[((size_t)b * 512 + g * 64 + ch) * 64 + tid];
        sums2[((size_t)b * 8 + g) * 64 + tid] = s;
    }
}

// ================= per-batch: reduce -> softmax(Wa G Wa^T + bias) -> u, cb =========
__launch_bounds__(256)
__global__ void attn_finish_v3(const float* __restrict__ part, const float* __restrict__ sums,
                               const float* __restrict__ wa, const float* __restrict__ ba,
                               const float* __restrict__ wf, const float* __restrict__ bf,
                               float* __restrict__ u, float* __restrict__ cb) {
    __shared__ float G[32][33];
    __shared__ float T[16][33];
    __shared__ float A[16][17];
    __shared__ float Sx[32], Ss[32], px[16], ps[16], v[16];
    const int b = blockIdx.x, tid = threadIdx.x;

    float a4[4] = {0.f, 0.f, 0.f, 0.f};
    for (int p = 0; p < 8; ++p) {
        const float* pp = part + ((size_t)b * 8 + p) * 1024 + tid;
        a4[0] += pp[0]; a4[1] += pp[256]; a4[2] += pp[512]; a4[3] += pp[768];
    }
    #pragma unroll
    for (int q = 0; q < 4; ++q) {
        const int t = tid + q * 256;
        G[t >> 5][t & 31] = a4[q];
    }
    if (tid < 64) {
        float s = 0.f;
        for (int p = 0; p < 8; ++p) s += sums[((size_t)b * 8 + p) * 64 + tid];
        if (tid < 32) Sx[tid] = s; else Ss[tid - 32] = s;
    }
    __syncthreads();
    for (int t = tid; t < 512; t += 256) {
        const int c = t >> 5, f = t & 31;
        float s = 0.f;
        #pragma unroll
        for (int e = 0; e < 32; ++e) s = fmaf(wa[c * 32 + e], G[e][f], s);
        T[c][f] = s;
    }
    if (tid < 32) {
        const int c = tid & 15;
        const float* S = (tid < 16) ? Sx : Ss;
        float s = 0.f;
        #pragma unroll
        for (int e = 0; e < 32; ++e) s = fmaf(wa[c * 32 + e], S[e], s);
        if (tid < 16) px[c] = s; else ps[c] = s;
    }
    __syncthreads();
    {
        const int c = tid >> 4, dd = tid & 15;
        float s = 0.f;
        #pragma unroll
        for (int f2 = 0; f2 < 32; ++f2) s = fmaf(T[c][f2], wa[dd * 32 + f2], s);
        s += px[c] * ba[dd] + ba[c] * ps[dd] + 65536.f * ba[c] * ba[dd];
        A[c][dd] = s;
    }
    __syncthreads();
    if (tid < 16) {
        float m = A[tid][0];
        #pragma unroll
        for (int dd = 1; dd < 16; ++dd) m = fmaxf(m, A[tid][dd]);
        float s = 0.f;
        #pragma unroll
        for (int dd = 0; dd < 16; ++dd) { const float e = __expf(A[tid][dd] - m); A[tid][dd] = e; s += e; }
        const float inv = 1.f / s;
        #pragma unroll
        for (int dd = 0; dd < 16; ++dd) A[tid][dd] *= inv;
    }
    __syncthreads();
    if (tid < 16) {
        float s = wf[tid];
        #pragma unroll
        for (int c = 0; c < 16; ++c) s = fmaf(wf[c], A[c][tid], s);
        v[tid] = s;
    }
    __syncthreads();
    if (tid < 32) {
        float s = 0.f;
        #pragma unroll
        for (int dd = 0; dd < 16; ++dd) s = fmaf(v[dd], wa[dd * 32 + tid], s);
        u[b * 32 + tid] = s;
    }
    if (tid == 0) {
        float s2 = bf[0];
        #pragma unroll
        for (int dd = 0; dd < 16; ++dd) s2 = fmaf(v[dd], ba[dd], s2);
        cb[b] = s2;
    }
}

// ================= final: out[b][n] = sigmoid(cb + u . x3cl[b][n][:]) ==============
__launch_bounds__(256)
__global__ void final_k(const f16* __restrict__ x3, const float* __restrict__ u,
                        const float* __restrict__ cb, float* __restrict__ out) {
    const int b = blockIdx.y;
    const int nn = blockIdx.x * 256 + threadIdx.x;
    const f16* xb = x3 + ((size_t)b * 65536 + nn) * 32;
    const float* ub = u + b * 32;
    float acc = cb[b];
    #pragma unroll
    for (int g = 0; g < 4; ++g) {
        const h8 v = *(const h8*)(xb + g * 8);
        #pragma unroll
        for (int q = 0; q < 8; ++q) acc = fmaf(ub[g * 8 + q], (float)v[q], acc);
    }
    out[(size_t)b * 65536 + nn] = sigmoid_f(acc);
}

extern "C" void kernel_launch(void* const* d_in, const int* in_sizes, int n_in,
                              void* d_out, int out_size, void* d_ws, size_t ws_size,
                              hipStream_t stream) {
    const float* enc   = (const float*)d_in[0];
    const float* sem   = (const float*)d_in[1];
    const float* wt0   = (const float*)d_in[2];
    const float* bt0   = (const float*)d_in[3];
    const float* wc0   = (const float*)d_in[4];
    const float* bc0   = (const float*)d_in[5];
    const float* wt1   = (const float*)d_in[6];
    const float* bt1   = (const float*)d_in[7];
    const float* wc1   = (const float*)d_in[8];
    const float* bc1   = (const float*)d_in[9];
    const float* wt2   = (const float*)d_in[10];
    const float* bt2   = (const float*)d_in[11];
    const float* wc2   = (const float*)d_in[12];
    const float* bc2   = (const float*)d_in[13];
    const float* wt3   = (const float*)d_in[14];
    const float* bt3   = (const float*)d_in[15];
    const float* wc3   = (const float*)d_in[16];
    const float* bc3   = (const float*)d_in[17];
    const float* wattn = (const float*)d_in[18];
    const float* battn = (const float*)d_in[19];
    const float* wfin  = (const float*)d_in[20];
    const float* bfin  = (const float*)d_in[21];

    char* W = (char*)d_ws;
    f16*   actA   = (f16*)(W + 0);            // 32 MB region (also pfA partials)
    f16*   actB   = (f16*)(W + 33554432);     // 32 MB region (pfB partials; L7 gram partials)
    f16*   x3cl   = (f16*)(W + 67108864);     // 32 MB: x3 channel-last
    f16*   wp     = (f16*)(W + 100663296);    // 4.7 MB
    f16*   enc_cl = (f16*)(W + 105906176);    // 2 MB
    // L7 gram partials live in the (then-dead) actB region:
    float* part   = (float*)(W + 33554432);   // 16 MB (8 x 512 x 1024 f32)
    float* sums   = (float*)(W + 50331648);   // 1 MB
    float* part2  = (float*)(W + 116916224);  // 256 KB
    float* sums2  = (float*)(W + 117178368);  // 16 KB
    float* u      = (float*)(W + 117194752);
    float* cb     = (float*)(W + 117195776);
    float* out    = (float*)d_out;
    f16* pfA = actA;
    f16* pfB = actB;

    P8 p;
    p.d[0] = {wt0, 0u,       256, 512, 1};
    p.d[1] = {wc0, 1179648u, 256, 256, 0};
    p.d[2] = {wt1, 1769472u, 128, 256, 1};
    p.d[3] = {wc1, 2064384u, 128, 128, 0};
    p.d[4] = {wt2, 2211840u,  64, 128, 1};
    p.d[5] = {wc2, 2285568u,  64,  64, 0};
    p.d[6] = {wt3, 2322432u,  32,  64, 1};
    p.d[7] = {wc3, 2340864u,  32,  32, 0};
    prep_all_k<<<9308, 256, 0, stream>>>(p, wp, enc, enc_cl);

    // L0: convT 512->256, KS=4 -> pfA (partials); pipelined staging
    convt_mfma<512, 256, 16, 16, 4, 1><<<dim3(4, 4, 64), 256, 0, stream>>>(
        enc_cl, wp, nullptr, nullptr, 0, nullptr, pfA);
    // L1: conv3 256ch, KS=4, fused-read L0 partials (SKS=4, bias bt0) -> pfB
    conv3_mfma<256, 32, 32, 8, 32, 2, 4, 4><<<dim3(4, 4, 64), 256, 0, stream>>>(
        pfA, wp + 1179648, nullptr, bt0, 2097152, nullptr, pfB);
    // L2: convT 256->128, KS=2, fused-read L1 partials (SKS=4, bias bc0) -> pfA
    convt_mfma<256, 128, 32, 32, 2, 4><<<dim3(4, 8, 32), 256, 0, stream>>>(
        pfB, wp + 1769472, nullptr, bc0, 2097152, nullptr, pfA);
    // L3: conv3 128ch, KS=2, fused-read L2 partials (SKS=2, bias bt1) -> pfB
    conv3_mfma<128, 64, 64, 4, 64, 4, 2, 2><<<dim3(2, 16, 32), 256, 0, stream>>>(
        pfA, wp + 2064384, nullptr, bt1, 4194304, nullptr, pfB);
    // L4: convT 128->64, direct out (bias bt2), fused-read L3 partials (SKS=2, bias bc1) -> actA
    convt_mfma<128, 64, 64, 64, 1, 2><<<dim3(4, 16, 16), 256, 0, stream>>>(
        pfB, wp + 2211840, bt2, bc1, 4194304, actA, nullptr);
    // L5: conv3 64ch (pipelined staging) -> actB
    conv3_mfma<64, 128, 128, 4, 64, 4, 1, 1><<<dim3(2, 32, 16), 256, 0, stream>>>(
        actA, wp + 2285568, bc2, nullptr, 0, actB, nullptr);
    // L6: convT 64->32 (pipelined staging) -> actA   (actB dead after this)
    convt_mfma<64, 32, 128, 128, 1, 1><<<dim3(8, 32, 8), 256, 0, stream>>>(
        actB, wp + 2322432, bt3, nullptr, 0, actA, nullptr);
    // L7: conv3 32ch + fused gram partials (HT=2, 4096 blocks, partials -> actB region)
    conv3_gram_k<<<dim3(4, 128, 8), 256, 0, stream>>>(
        actA, wp + 2340864, bc3, sem, x3cl, part, sums);

    gram_reduce_k<<<dim3(8, 8), 256, 0, stream>>>(part, sums, part2, sums2);
    attn_finish_v3<<<8, 256, 0, stream>>>(part2, sums2, wattn, battn, wfin, bfin, u, cb);
    final_k<<<dim3(256, 8), 256, 0, stream>>>(x3cl, u, cb, out);
}

// Round 18
// 220.961 us; speedup vs baseline: 1.0530x; 1.0530x over previous
//
#include <hip/hip_runtime.h>
#include <hip/hip_bf16.h>
#include <math.h>

typedef _Float16 f16;
typedef _Float16 h8 __attribute__((ext_vector_type(8)));
typedef _Float16 h4 __attribute__((ext_vector_type(4)));
typedef float    f4 __attribute__((ext_vector_type(4)));

__device__ __forceinline__ float elu_f(float v) { return v > 0.f ? v : __expf(v) - 1.f; }
__device__ __forceinline__ float sigmoid_f(float v) { return 1.f / (1.f + __expf(-v)); }

// ===== combined prep: enc transpose (blocks 0..127) + fragment-ordered weights =====
struct PrepDesc { const float* src; unsigned dstOff; int OC; int IC; int tr; };
struct P8 { PrepDesc d[8]; };

__global__ void prep_all_k(P8 p, f16* __restrict__ wp,
                           const float* __restrict__ enc, f16* __restrict__ enc_cl) {
    __shared__ float ts[32][257];
    if (blockIdx.x < 128) {
        const int b = blockIdx.x >> 4, cg = blockIdx.x & 15;
        const int tid = threadIdx.x;
        #pragma unroll
        for (int i = 0; i < 32; ++i)
            ts[i][tid] = enc[((size_t)(b * 512 + cg * 32 + i)) * 256 + tid];
        __syncthreads();
        #pragma unroll
        for (int k = 0; k < 4; ++k) {
            h8 v;
            #pragma unroll
            for (int q = 0; q < 8; ++q) v[q] = (f16)ts[k * 8 + q][tid];
            *(h8*)(enc_cl + ((size_t)(b * 256 + tid)) * 512 + cg * 32 + k * 8) = v;
        }
        return;
    }
    unsigned idx = (blockIdx.x - 128) * 256u + threadIdx.x;
    for (int s = 0; s < 8; ++s) {
        const int IC = p.d[s].IC, OC = p.d[s].OC;
        const unsigned cnt = (unsigned)(OC * 9 * IC);
        if (idx < cnt) {
            const int nicc = IC >> 5;
            const int j    = idx & 7;
            const int lane = (idx >> 3) & 63;
            const int mt   = (idx >> 9) & 1;
            unsigned r = idx >> 10;
            const int tap = r % 9;  r /= 9;
            const int icchunk = r % nicc;
            const int ocg     = r / nicc;
            const int oc = ocg * 32 + mt * 16 + (lane & 15);
            const int ic = icchunk * 32 + (lane >> 4) * 8 + j;
            const float v = p.d[s].tr ? p.d[s].src[((size_t)ic * OC + oc) * 9 + tap]
                                      : p.d[s].src[((size_t)oc * IC + ic) * 9 + tap];
            wp[p.d[s].dstOff + idx] = (f16)v;
            return;
        }
        idx -= cnt;
    }
}

// ===== fused staging element: sum SKS partials + producer bias + ELU =====
template<int SKS>
__device__ __forceinline__ h8 stage_elem(const f16* __restrict__ in, size_t off,
                                         size_t srcTot, const float* __restrict__ sbias,
                                         int ch0) {
    if constexpr (SKS == 1) {
        return *(const h8*)(in + off);
    } else {
        float s[8];
        const h8 t0 = *(const h8*)(in + off);
        #pragma unroll
        for (int j = 0; j < 8; ++j) s[j] = (float)t0[j];
        #pragma unroll
        for (int k = 1; k < SKS; ++k) {
            const h8 tk = *(const h8*)(in + (size_t)k * srcTot + off);
            #pragma unroll
            for (int j = 0; j < 8; ++j) s[j] += (float)tk[j];
        }
        const float4 b0 = *(const float4*)(sbias + ch0);
        const float4 b1 = *(const float4*)(sbias + ch0 + 4);
        h8 v;
        v[0] = (f16)elu_f(s[0] + b0.x); v[1] = (f16)elu_f(s[1] + b0.y);
        v[2] = (f16)elu_f(s[2] + b0.z); v[3] = (f16)elu_f(s[3] + b0.w);
        v[4] = (f16)elu_f(s[4] + b1.x); v[5] = (f16)elu_f(s[5] + b1.y);
        v[6] = (f16)elu_f(s[6] + b1.z); v[7] = (f16)elu_f(s[7] + b1.w);
        return v;
    }
}

// ================= Conv2d(k3,p1)+ELU via MFMA, channel-last f16 ====================
template<int C, int H, int W, int HT, int WT, int NWN, int KS, int SKS>
__launch_bounds__(256, 2)
__global__ void conv3_mfma(const f16* __restrict__ in, const f16* __restrict__ wp,
                           const float* __restrict__ bias, const float* __restrict__ sbias,
                           size_t srcTot, f16* __restrict__ out, f16* __restrict__ pout) {
    constexpr int NWR = 4 / NWN;
    constexpr int RH  = HT / NWR;
    constexpr int PIXR = WT + 2;
    constexpr int ROWS = HT + 2;
    constexpr int XB = ROWS * PIXR * 80;
    constexpr int NICC = C / 32;
    constexpr int XTILES = W / WT;
    constexpr int NLD = ROWS * PIXR * 4;
    constexpr int NIT = (NLD + 255) / 256;
    constexpr int CPB = C / KS / 32;
    __shared__ __align__(16) char xlds[XB];

    const int tid = threadIdx.x;
    const int wid = tid >> 6, lane = tid & 63;
    const int ln15 = lane & 15, lg = lane >> 4;
    const int ni = wid % NWN, ri = wid / NWN;
    const int bz = blockIdx.z;
    const int bb = bz / (C / 32), ocg = bz % (C / 32);
    const int oc0 = ocg * 32;
    const int bx = blockIdx.x;
    const int xt = bx % XTILES, ks = bx / XTILES;
    const int h0 = blockIdx.y * HT, w0 = xt * WT;
    const int colb = ni * 16 + ln15;

    f4 acc[RH][2] = {};

    auto compute_chunk = [&](int icc) {
        const f16* wbl = wp + ((size_t)(ocg * NICC + (icc >> 5)) * 18) * 512 + lane * 8;
        #pragma unroll
        for (int dw = 0; dw < 3; ++dw) {
            h8 afd[3][2];
            #pragma unroll
            for (int dh = 0; dh < 3; ++dh)
                #pragma unroll
                for (int mt = 0; mt < 2; ++mt)
                    afd[dh][mt] = *(const h8*)(wbl + ((dh * 3 + dw) * 2 + mt) * 512);
            h8 bfv[RH + 2];
            #pragma unroll
            for (int q = 0; q < RH + 2; ++q)
                bfv[q] = *(const h8*)(xlds + ((ri * RH + q) * PIXR + colb + dw) * 80 + lg * 16);
            #pragma unroll
            for (int r = 0; r < RH; ++r) {
                #pragma unroll
                for (int dh = 0; dh < 3; ++dh) {
                    acc[r][0] = __builtin_amdgcn_mfma_f32_16x16x32_f16(afd[dh][0], bfv[r + dh], acc[r][0], 0, 0, 0);
                    acc[r][1] = __builtin_amdgcn_mfma_f32_16x16x32_f16(afd[dh][1], bfv[r + dh], acc[r][1], 0, 0, 0);
                }
            }
        }
    };

    if constexpr (SKS == 1 && CPB > 1) {
        h8 pre[NIT];
        const int icc0 = ks * (C / KS);
        auto do_loads = [&](int icc) {
            #pragma unroll
            for (int i = 0; i < NIT; ++i) {
                const int t = tid + i * 256;
                if (t < NLD) {
                    const int g = t & 3, pix = t >> 2;
                    const int rr = pix / PIXR, ww = pix - rr * PIXR;
                    const int gh = h0 - 1 + rr, gw = w0 - 1 + ww;
                    h8 v = {};
                    if (gh >= 0 && gh < H && gw >= 0 && gw < W)
                        v = *(const h8*)(in + (((size_t)bb * H + gh) * W + gw) * C + icc + g * 8);
                    pre[i] = v;
                }
            }
        };
        do_loads(icc0);
        for (int ci = 0; ci < CPB; ++ci) {
            __syncthreads();
            #pragma unroll
            for (int i = 0; i < NIT; ++i) {
                const int t = tid + i * 256;
                if (t < NLD) {
                    const int g = t & 3, pix = t >> 2;
                    *(h8*)(xlds + pix * 80 + g * 16) = pre[i];
                }
            }
            __syncthreads();
            if (ci + 1 < CPB) do_loads(icc0 + (ci + 1) * 32);
            compute_chunk(icc0 + ci * 32);
        }
    } else {
        for (int icc = ks * (C / KS); icc < (ks + 1) * (C / KS); icc += 32) {
            __syncthreads();
            for (int t = tid; t < NLD; t += 256) {
                const int g = t & 3, pix = t >> 2;
                const int rr = pix / PIXR, ww = pix - rr * PIXR;
                const int gh = h0 - 1 + rr, gw = w0 - 1 + ww;
                h8 v = {};
                if (gh >= 0 && gh < H && gw >= 0 && gw < W) {
                    const size_t off = (((size_t)bb * H + gh) * W + gw) * C + icc + g * 8;
                    v = stage_elem<SKS>(in, off, srcTot, sbias, icc + g * 8);
                }
                *(h8*)(xlds + pix * 80 + g * 16) = v;
            }
            __syncthreads();
            compute_chunk(icc);
        }
    }

    #pragma unroll
    for (int r = 0; r < RH; ++r) {
        const int oh = h0 + ri * RH + r;
        const int ow = w0 + colb;
        #pragma unroll
        for (int mt = 0; mt < 2; ++mt) {
            const int ocl = mt * 16 + lg * 4;
            const f4 v = acc[r][mt];
            if constexpr (KS > 1) {
                const size_t TOT = (size_t)8 * H * W * C;
                h4 hv = {(f16)v.x, (f16)v.y, (f16)v.z, (f16)v.w};
                *(h4*)(pout + (size_t)ks * TOT +
                       (((size_t)bb * H + oh) * W + ow) * C + oc0 + ocl) = hv;
            } else {
                const float4 b4 = *(const float4*)(bias + oc0 + ocl);
                h4 hv = {(f16)elu_f(v.x + b4.x), (f16)elu_f(v.y + b4.y),
                         (f16)elu_f(v.z + b4.z), (f16)elu_f(v.w + b4.w)};
                *(h4*)(out + (((size_t)bb * H + oh) * W + ow) * C + oc0 + ocl) = hv;
            }
        }
    }
}

// ================= ConvTranspose2d(k3,s2,p1,op1)+ELU via MFMA ======================
template<int IC, int OC, int Hi, int Wi, int KS, int SKS>
__launch_bounds__(256, 2)
__global__ void convt_mfma(const f16* __restrict__ in, const f16* __restrict__ wp,
                           const float* __restrict__ bias, const float* __restrict__ sbias,
                           size_t srcTot, f16* __restrict__ out, f16* __restrict__ pout) {
    constexpr int HT = 4, WT = 16;
    constexpr int PIXR = WT + 1;
    constexpr int ROWS = HT + 1;
    constexpr int XB = ROWS * PIXR * 80;
    constexpr int NICC = IC / 32;
    constexpr int XTILES = Wi / WT;
    constexpr int NLD = ROWS * PIXR * 4;
    constexpr int NIT = (NLD + 255) / 256;
    constexpr int CPB = IC / KS / 32;
    __shared__ __align__(16) char xlds[XB];

    const int tid = threadIdx.x;
    const int wid = tid >> 6, lane = tid & 63;
    const int ln15 = lane & 15, lg = lane >> 4;
    const int iloc = wid;
    const int bz = blockIdx.z;
    const int bb = bz / (OC / 32), ocg = bz % (OC / 32);
    const int oc0 = ocg * 32;
    const int bx = blockIdx.x;
    const int xt = bx % XTILES, ks = bx / XTILES;
    const int i0 = blockIdx.y * HT, j0 = xt * WT;

    f4 acc[4][2] = {};

    auto compute_chunk = [&](int icc) {
        const f16* wbl = wp + ((size_t)(ocg * NICC + (icc >> 5)) * 18) * 512 + lane * 8;
        h8 af[9][2];
        #pragma unroll
        for (int tap = 0; tap < 9; ++tap)
            #pragma unroll
            for (int mt = 0; mt < 2; ++mt)
                af[tap][mt] = *(const h8*)(wbl + (tap * 2 + mt) * 512);

        h8 bf[2][2];
        #pragma unroll
        for (int a = 0; a < 2; ++a)
            #pragma unroll
            for (int b = 0; b < 2; ++b)
                bf[a][b] = *(const h8*)(xlds + ((iloc + a) * PIXR + ln15 + b) * 80 + lg * 16);

        #pragma unroll
        for (int p = 0; p < 4; ++p) {
            const int di = p >> 1, dj = p & 1;
            #pragma unroll
            for (int a = 0; a < 2; ++a) {
                if (a > di) continue;
                const int kh = 1 + di - 2 * a;
                #pragma unroll
                for (int b = 0; b < 2; ++b) {
                    if (b > dj) continue;
                    const int kw = 1 + dj - 2 * b;
                    const int tap = kh * 3 + kw;
                    acc[p][0] = __builtin_amdgcn_mfma_f32_16x16x32_f16(af[tap][0], bf[a][b], acc[p][0], 0, 0, 0);
                    acc[p][1] = __builtin_amdgcn_mfma_f32_16x16x32_f16(af[tap][1], bf[a][b], acc[p][1], 0, 0, 0);
                }
            }
        }
    };

    if constexpr (SKS == 1 && CPB > 1) {
        h8 pre[NIT];
        const int icc0 = ks * (IC / KS);
        auto do_loads = [&](int icc) {
            #pragma unroll
            for (int i = 0; i < NIT; ++i) {
                const int t = tid + i * 256;
                if (t < NLD) {
                    const int g = t & 3, pix = t >> 2;
                    const int rr = pix / PIXR, ww = pix - rr * PIXR;
                    const int gh = i0 + rr, gw = j0 + ww;
                    h8 v = {};
                    if (gh < Hi && gw < Wi)
                        v = *(const h8*)(in + (((size_t)bb * Hi + gh) * Wi + gw) * IC + icc + g * 8);
                    pre[i] = v;
                }
            }
        };
        do_loads(icc0);
        for (int ci = 0; ci < CPB; ++ci) {
            __syncthreads();
            #pragma unroll
            for (int i = 0; i < NIT; ++i) {
                const int t = tid + i * 256;
                if (t < NLD) {
                    const int g = t & 3, pix = t >> 2;
                    *(h8*)(xlds + pix * 80 + g * 16) = pre[i];
                }
            }
            __syncthreads();
            if (ci + 1 < CPB) do_loads(icc0 + (ci + 1) * 32);
            compute_chunk(icc0 + ci * 32);
        }
    } else {
        for (int icc = ks * (IC / KS); icc < (ks + 1) * (IC / KS); icc += 32) {
            __syncthreads();
            for (int t = tid; t < NLD; t += 256) {
                const int g = t & 3, pix = t >> 2;
                const int rr = pix / PIXR, ww = pix - rr * PIXR;
                const int gh = i0 + rr, gw = j0 + ww;
                h8 v = {};
                if (gh < Hi && gw < Wi) {
                    const size_t off = (((size_t)bb * Hi + gh) * Wi + gw) * IC + icc + g * 8;
                    v = stage_elem<SKS>(in, off, srcTot, sbias, icc + g * 8);
                }
                *(h8*)(xlds + pix * 80 + g * 16) = v;
            }
            __syncthreads();
            compute_chunk(icc);
        }
    }

    #pragma unroll
    for (int p = 0; p < 4; ++p) {
        const int orow = 2 * (i0 + iloc) + (p >> 1);
        const int ocol = 2 * (j0 + ln15) + (p & 1);
        #pragma unroll
        for (int mt = 0; mt < 2; ++mt) {
            const int ocl = mt * 16 + lg * 4;
            const f4 v = acc[p][mt];
            if constexpr (KS > 1) {
                const size_t TOT = (size_t)8 * (2 * Hi) * (2 * Wi) * OC;
                h4 hv = {(f16)v.x, (f16)v.y, (f16)v.z, (f16)v.w};
                *(h4*)(pout + (size_t)ks * TOT +
                       (((size_t)bb * (2 * Hi) + orow) * (2 * Wi) + ocol) * OC + oc0 + ocl) = hv;
            } else {
                const float4 b4 = *(const float4*)(bias + oc0 + ocl);
                h4 hv = {(f16)elu_f(v.x + b4.x), (f16)elu_f(v.y + b4.y),
                         (f16)elu_f(v.z + b4.z), (f16)elu_f(v.w + b4.w)};
                *(h4*)(out + (((size_t)bb * (2 * Hi) + orow) * (2 * Wi) + ocol) * OC + oc0 + ocl) = hv;
            }
        }
    }
}

// ======== L7 conv3(32ch,256²) + fused Gram partials (sem prefetched early) ========
__launch_bounds__(256, 2)
__global__ void conv3_gram_k(const f16* __restrict__ in, const f16* __restrict__ wp,
                             const float* __restrict__ bias, const float* __restrict__ sem,
                             f16* __restrict__ out, float* __restrict__ part,
                             float* __restrict__ sums) {
    constexpr int C = 32, H = 256, W = 256, HT = 4, WT = 64;
    constexpr int PIXR = WT + 2;               // 66
    constexpr int ROWS = HT + 2;               // 6
    constexpr int XB = ROWS * PIXR * 80;       // 31680
    constexpr int X3B = 32 * 264 * 2;          // 16896
    constexpr int LDSB = X3B + 16384 + 1024;
    __shared__ __align__(16) char lds[(XB > LDSB) ? XB : LDSB];
    char* xlds = lds;
    f16*   x3l = (f16*)lds;
    float* pl  = (float*)(lds + X3B);
    float* sl  = (float*)(lds + X3B + 16384);

    const int tid = threadIdx.x;
    const int wid = tid >> 6, lane = tid & 63;
    const int ln15 = lane & 15, lg = lane >> 4;
    const int ni = wid;
    const int bb = blockIdx.z;
    const int h0 = blockIdx.y * HT, w0 = blockIdx.x * WT;
    const int colb = ni * 16 + ln15;

    // ---- conv input staging (loads issue first) ----
    for (int t = tid; t < ROWS * PIXR * 4; t += 256) {
        const int g = t & 3, pix = t >> 2;
        const int rr = pix / PIXR, ww = pix - rr * PIXR;
        const int gh = h0 - 1 + rr, gw = w0 - 1 + ww;
        h8 v = {};
        if (gh >= 0 && gh < H && gw >= 0 && gw < W)
            v = *(const h8*)(in + (((size_t)bb * H + gh) * W + gw) * C + g * 8);
        *(h8*)(xlds + pix * 80 + g * 16) = v;
    }

    // ---- prefetch sem for the gram phase (consumed 2 barriers later) ----
    const int row = ln15, kg = lg;
    const size_t N = 65536;
    const float* sb = sem + ((size_t)bb * 32 + row) * N + (size_t)(h0 + wid) * 256 + w0 + kg * 8;
    float4 semr[8];
    #pragma unroll
    for (int ks2 = 0; ks2 < 2; ++ks2) {
        const int k0 = ks2 * 32;
        semr[ks2 * 4 + 0] = *(const float4*)(sb + k0);
        semr[ks2 * 4 + 1] = *(const float4*)(sb + k0 + 4);
        semr[ks2 * 4 + 2] = *(const float4*)(sb + 16 * N + k0);
        semr[ks2 * 4 + 3] = *(const float4*)(sb + 16 * N + k0 + 4);
    }
    __syncthreads();

    f4 acc[4][2] = {};
    const f16* wbl = wp + lane * 8;
    #pragma unroll
    for (int dw = 0; dw < 3; ++dw) {
        h8 afd[3][2];
        #pragma unroll
        for (int dh = 0; dh < 3; ++dh)
            #pragma unroll
            for (int mt = 0; mt < 2; ++mt)
                afd[dh][mt] = *(const h8*)(wbl + ((dh * 3 + dw) * 2 + mt) * 512);
        h8 bfv[6];
        #pragma unroll
        for (int q = 0; q < 6; ++q)
            bfv[q] = *(const h8*)(xlds + (q * PIXR + colb + dw) * 80 + lg * 16);
        #pragma unroll
        for (int r = 0; r < 4; ++r) {
            #pragma unroll
            for (int dh = 0; dh < 3; ++dh) {
                acc[r][0] = __builtin_amdgcn_mfma_f32_16x16x32_f16(afd[dh][0], bfv[r + dh], acc[r][0], 0, 0, 0);
                acc[r][1] = __builtin_amdgcn_mfma_f32_16x16x32_f16(afd[dh][1], bfv[r + dh], acc[r][1], 0, 0, 0);
            }
        }
    }
    __syncthreads();   // xlds reads done -> safe to overwrite with x3l

    // ---- epilogue: bias+ELU -> global x3cl + LDS x3l[ch][264] ----
    #pragma unroll
    for (int r = 0; r < 4; ++r) {
        const int oh = h0 + r, ow = w0 + colb;
        const int px = r * 64 + colb;
        #pragma unroll
        for (int mt = 0; mt < 2; ++mt) {
            const int ocl = mt * 16 + lg * 4;
            const float4 b4 = *(const float4*)(bias + ocl);
            const f4 v = acc[r][mt];
            h4 hv = {(f16)elu_f(v.x + b4.x), (f16)elu_f(v.y + b4.y),
                     (f16)elu_f(v.z + b4.z), (f16)elu_f(v.w + b4.w)};
            *(h4*)(out + (((size_t)bb * H + oh) * W + ow) * C + ocl) = hv;
            x3l[(ocl + 0) * 264 + px] = hv[0];
            x3l[(ocl + 1) * 264 + px] = hv[1];
            x3l[(ocl + 2) * 264 + px] = hv[2];
            x3l[(ocl + 3) * 264 + px] = hv[3];
        }
    }
    __syncthreads();

    // ---- gram: wave `wid` handles its 64 px row, sem from registers ----
    f4 g00 = {}, g01 = {}, g10 = {}, g11 = {};
    float sx0 = 0.f, sx1 = 0.f, ss0 = 0.f, ss1 = 0.f;

    #pragma unroll
    for (int ks2 = 0; ks2 < 2; ++ks2) {
        const int k0 = ks2 * 32;
        const h8 a0 = *(const h8*)(x3l + row * 264 + wid * 64 + k0 + kg * 8);
        const h8 a1 = *(const h8*)(x3l + (row + 16) * 264 + wid * 64 + k0 + kg * 8);
        const float4 f0 = semr[ks2 * 4 + 0];
        const float4 f1 = semr[ks2 * 4 + 1];
        const float4 q0 = semr[ks2 * 4 + 2];
        const float4 q1 = semr[ks2 * 4 + 3];
        const h8 b0 = {(f16)f0.x, (f16)f0.y, (f16)f0.z, (f16)f0.w,
                       (f16)f1.x, (f16)f1.y, (f16)f1.z, (f16)f1.w};
        const h8 b1 = {(f16)q0.x, (f16)q0.y, (f16)q0.z, (f16)q0.w,
                       (f16)q1.x, (f16)q1.y, (f16)q1.z, (f16)q1.w};
        g00 = __builtin_amdgcn_mfma_f32_16x16x32_f16(a0, b0, g00, 0, 0, 0);
        g01 = __builtin_amdgcn_mfma_f32_16x16x32_f16(a0, b1, g01, 0, 0, 0);
        g10 = __builtin_amdgcn_mfma_f32_16x16x32_f16(a1, b0, g10, 0, 0, 0);
        g11 = __builtin_amdgcn_mfma_f32_16x16x32_f16(a1, b1, g11, 0, 0, 0);
        #pragma unroll
        for (int q = 0; q < 8; ++q) { sx0 += (float)a0[q]; sx1 += (float)a1[q]; }
        ss0 += (f0.x + f0.y + f0.z + f0.w) + (f1.x + f1.y + f1.z + f1.w);
        ss1 += (q0.x + q0.y + q0.z + q0.w) + (q1.x + q1.y + q1.z + q1.w);
    }

    sx0 += __shfl_xor(sx0, 16); sx0 += __shfl_xor(sx0, 32);
    sx1 += __shfl_xor(sx1, 16); sx1 += __shfl_xor(sx1, 32);
    ss0 += __shfl_xor(ss0, 16); ss0 += __shfl_xor(ss0, 32);
    ss1 += __shfl_xor(ss1, 16); ss1 += __shfl_xor(ss1, 32);

    #pragma unroll
    for (int reg = 0; reg < 4; ++reg) {
        const int c0 = 4 * kg + reg;
        pl[wid * 1024 + c0 * 32 + row]             = g00[reg];
        pl[wid * 1024 + c0 * 32 + 16 + row]        = g01[reg];
        pl[wid * 1024 + (16 + c0) * 32 + row]      = g10[reg];
        pl[wid * 1024 + (16 + c0) * 32 + 16 + row] = g11[reg];
    }
    if (lane < 16) {
        sl[wid * 64 + row]      = sx0;
        sl[wid * 64 + 16 + row] = sx1;
        sl[wid * 64 + 32 + row] = ss0;
        sl[wid * 64 + 48 + row] = ss1;
    }
    __syncthreads();

    const int chunk = blockIdx.y * 4 + blockIdx.x;       // 0..255
    float* pb = part + ((size_t)bb * 256 + chunk) * 1024;
    for (int t = tid; t < 1024; t += 256)
        pb[t] = pl[t] + pl[1024 + t] + pl[2048 + t] + pl[3072 + t];
    if (tid < 64)
        sums[((size_t)bb * 256 + chunk) * 64 + tid] = sl[tid] + sl[64 + tid] + sl[128 + tid] + sl[192 + tid];
}

// ================= two-level reduce: 256 partials -> 8 ============================
__launch_bounds__(256)
__global__ void gram_reduce_k(const float* __restrict__ part, const float* __restrict__ sums,
                              float* __restrict__ part2, float* __restrict__ sums2) {
    const int b = blockIdx.y, g = blockIdx.x;
    const int tid = threadIdx.x;
    const int i4 = tid * 4;
    f4 a = {};
    #pragma unroll 4
    for (int ch = 0; ch < 32; ++ch) {
        const f4 v = *(const f4*)(part + ((size_t)b * 256 + g * 32 + ch) * 1024 + i4);
        a.x += v.x; a.y += v.y; a.z += v.z; a.w += v.w;
    }
    *(f4*)(part2 + ((size_t)b * 8 + g) * 1024 + i4) = a;
    if (tid < 64) {
        float s = 0.f;
        #pragma unroll 4
        for (int ch = 0; ch < 32; ++ch) s += sums[((size_t)b * 256 + g * 32 + ch) * 64 + tid];
        sums2[((size_t)b * 8 + g) * 64 + tid] = s;
    }
}

// ================= per-batch: reduce -> softmax(Wa G Wa^T + bias) -> u, cb =========
__launch_bounds__(256)
__global__ void attn_finish_v3(const float* __restrict__ part, const float* __restrict__ sums,
                               const float* __restrict__ wa, const float* __restrict__ ba,
                               const float* __restrict__ wf, const float* __restrict__ bf,
                               float* __restrict__ u, float* __restrict__ cb) {
    __shared__ float G[32][33];
    __shared__ float T[16][33];
    __shared__ float A[16][17];
    __shared__ float Sx[32], Ss[32], px[16], ps[16], v[16];
    const int b = blockIdx.x, tid = threadIdx.x;

    float a4[4] = {0.f, 0.f, 0.f, 0.f};
    for (int p = 0; p < 8; ++p) {
        const float* pp = part + ((size_t)b * 8 + p) * 1024 + tid;
        a4[0] += pp[0]; a4[1] += pp[256]; a4[2] += pp[512]; a4[3] += pp[768];
    }
    #pragma unroll
    for (int q = 0; q < 4; ++q) {
        const int t = tid + q * 256;
        G[t >> 5][t & 31] = a4[q];
    }
    if (tid < 64) {
        float s = 0.f;
        for (int p = 0; p < 8; ++p) s += sums[((size_t)b * 8 + p) * 64 + tid];
        if (tid < 32) Sx[tid] = s; else Ss[tid - 32] = s;
    }
    __syncthreads();
    for (int t = tid; t < 512; t += 256) {
        const int c = t >> 5, f = t & 31;
        float s = 0.f;
        #pragma unroll
        for (int e = 0; e < 32; ++e) s = fmaf(wa[c * 32 + e], G[e][f], s);
        T[c][f] = s;
    }
    if (tid < 32) {
        const int c = tid & 15;
        const float* S = (tid < 16) ? Sx : Ss;
        float s = 0.f;
        #pragma unroll
        for (int e = 0; e < 32; ++e) s = fmaf(wa[c * 32 + e], S[e], s);
        if (tid < 16) px[c] = s; else ps[c] = s;
    }
    __syncthreads();
    {
        const int c = tid >> 4, d = tid & 15;
        float s = 0.f;
        #pragma unroll
        for (int f2 = 0; f2 < 32; ++f2) s = fmaf(T[c][f2], wa[d * 32 + f2], s);
        s += px[c] * ba[d] + ba[c] * ps[d] + 65536.f * ba[c] * ba[d];
        A[c][d] = s;
    }
    __syncthreads();
    if (tid < 16) {
        float m = A[tid][0];
        #pragma unroll
        for (int d = 1; d < 16; ++d) m = fmaxf(m, A[tid][d]);
        float s = 0.f;
        #pragma unroll
        for (int d = 0; d < 16; ++d) { const float e = __expf(A[tid][d] - m); A[tid][d] = e; s += e; }
        const float inv = 1.f / s;
        #pragma unroll
        for (int d = 0; d < 16; ++d) A[tid][d] *= inv;
    }
    __syncthreads();
    if (tid < 16) {
        float s = wf[tid];
        #pragma unroll
        for (int c = 0; c < 16; ++c) s = fmaf(wf[c], A[c][tid], s);
        v[tid] = s;
    }
    __syncthreads();
    if (tid < 32) {
        float s = 0.f;
        #pragma unroll
        for (int d = 0; d < 16; ++d) s = fmaf(v[d], wa[d * 32 + tid], s);
        u[b * 32 + tid] = s;
    }
    if (tid == 0) {
        float s2 = bf[0];
        #pragma unroll
        for (int d = 0; d < 16; ++d) s2 = fmaf(v[d], ba[d], s2);
        cb[b] = s2;
    }
}

// ================= final: out[b][n] = sigmoid(cb + u . x3cl[b][n][:]) ==============
__launch_bounds__(256)
__global__ void final_k(const f16* __restrict__ x3, const float* __restrict__ u,
                        const float* __restrict__ cb, float* __restrict__ out) {
    const int b = blockIdx.y;
    const int nn = blockIdx.x * 256 + threadIdx.x;
    const f16* xb = x3 + ((size_t)b * 65536 + nn) * 32;
    const float* ub = u + b * 32;
    float acc = cb[b];
    #pragma unroll
    for (int g = 0; g < 4; ++g) {
        const h8 v = *(const h8*)(xb + g * 8);
        #pragma unroll
        for (int q = 0; q < 8; ++q) acc = fmaf(ub[g * 8 + q], (float)v[q], acc);
    }
    out[(size_t)b * 65536 + nn] = sigmoid_f(acc);
}

extern "C" void kernel_launch(void* const* d_in, const int* in_sizes, int n_in,
                              void* d_out, int out_size, void* d_ws, size_t ws_size,
                              hipStream_t stream) {
    const float* enc   = (const float*)d_in[0];
    const float* sem   = (const float*)d_in[1];
    const float* wt0   = (const float*)d_in[2];
    const float* bt0   = (const float*)d_in[3];
    const float* wc0   = (const float*)d_in[4];
    const float* bc0   = (const float*)d_in[5];
    const float* wt1   = (const float*)d_in[6];
    const float* bt1   = (const float*)d_in[7];
    const float* wc1   = (const float*)d_in[8];
    const float* bc1   = (const float*)d_in[9];
    const float* wt2   = (const float*)d_in[10];
    const float* bt2   = (const float*)d_in[11];
    const float* wc2   = (const float*)d_in[12];
    const float* bc2   = (const float*)d_in[13];
    const float* wt3   = (const float*)d_in[14];
    const float* bt3   = (const float*)d_in[15];
    const float* wc3   = (const float*)d_in[16];
    const float* bc3   = (const float*)d_in[17];
    const float* wattn = (const float*)d_in[18];
    const float* battn = (const float*)d_in[19];
    const float* wfin  = (const float*)d_in[20];
    const float* bfin  = (const float*)d_in[21];

    char* W = (char*)d_ws;
    f16*   actA   = (f16*)(W + 0);            // 32 MB region (also pfA partials)
    f16*   actB   = (f16*)(W + 33554432);     // 32 MB region (also pfB partials)
    f16*   x3cl   = (f16*)(W + 67108864);     // 32 MB: x3 channel-last
    f16*   wp     = (f16*)(W + 100663296);    // 4.7 MB
    f16*   enc_cl = (f16*)(W + 105906176);    // 2 MB
    float* part   = (float*)(W + 108003328);  // 8 MB (8 x 256 x 1024)
    float* sums   = (float*)(W + 116391936);  // 512 KB
    float* part2  = (float*)(W + 116916224);  // 256 KB
    float* sums2  = (float*)(W + 117178368);  // 16 KB
    float* u      = (float*)(W + 117194752);
    float* cb     = (float*)(W + 117195776);
    float* out    = (float*)d_out;
    f16* pfA = actA;
    f16* pfB = actB;

    P8 p;
    p.d[0] = {wt0, 0u,       256, 512, 1};
    p.d[1] = {wc0, 1179648u, 256, 256, 0};
    p.d[2] = {wt1, 1769472u, 128, 256, 1};
    p.d[3] = {wc1, 2064384u, 128, 128, 0};
    p.d[4] = {wt2, 2211840u,  64, 128, 1};
    p.d[5] = {wc2, 2285568u,  64,  64, 0};
    p.d[6] = {wt3, 2322432u,  32,  64, 1};
    p.d[7] = {wc3, 2340864u,  32,  32, 0};
    prep_all_k<<<9308, 256, 0, stream>>>(p, wp, enc, enc_cl);

    // L0: convT 512->256, KS=4 -> pfA (partials); pipelined staging
    convt_mfma<512, 256, 16, 16, 4, 1><<<dim3(4, 4, 64), 256, 0, stream>>>(
        enc_cl, wp, nullptr, nullptr, 0, nullptr, pfA);
    // L1: conv3 256ch, KS=4, fused-read L0 partials (SKS=4, bias bt0) -> pfB
    conv3_mfma<256, 32, 32, 8, 32, 2, 4, 4><<<dim3(4, 4, 64), 256, 0, stream>>>(
        pfA, wp + 1179648, nullptr, bt0, 2097152, nullptr, pfB);
    // L2: convT 256->128, KS=2, fused-read L1 partials (SKS=4, bias bc0) -> pfA
    convt_mfma<256, 128, 32, 32, 2, 4><<<dim3(4, 8, 32), 256, 0, stream>>>(
        pfB, wp + 1769472, nullptr, bc0, 2097152, nullptr, pfA);
    // L3: conv3 128ch, KS=2, fused-read L2 partials (SKS=2, bias bt1) -> pfB
    conv3_mfma<128, 64, 64, 4, 64, 4, 2, 2><<<dim3(2, 16, 32), 256, 0, stream>>>(
        pfA, wp + 2064384, nullptr, bt1, 4194304, nullptr, pfB);
    // L4: convT 128->64, direct out (bias bt2), fused-read L3 partials (SKS=2, bias bc1) -> actA
    convt_mfma<128, 64, 64, 64, 1, 2><<<dim3(4, 16, 16), 256, 0, stream>>>(
        pfB, wp + 2211840, bt2, bc1, 4194304, actA, nullptr);
    // L5: conv3 64ch (pipelined staging)
    conv3_mfma<64, 128, 128, 4, 64, 4, 1, 1><<<dim3(2, 32, 16), 256, 0, stream>>>(
        actA, wp + 2285568, bc2, nullptr, 0, actB, nullptr);
    // L6: convT 64->32 (pipelined staging)
    convt_mfma<64, 32, 128, 128, 1, 1><<<dim3(8, 32, 8), 256, 0, stream>>>(
        actB, wp + 2322432, bt3, nullptr, 0, actA, nullptr);
    // L7: conv3 32ch + fused gram partials (sem prefetched)
    conv3_gram_k<<<dim3(4, 64, 8), 256, 0, stream>>>(
        actA, wp + 2340864, bc3, sem, x3cl, part, sums);

    gram_reduce_k<<<dim3(8, 8), 256, 0, stream>>>(part, sums, part2, sums2);
    attn_finish_v3<<<8, 256, 0, stream>>>(part2, sums2, wattn, battn, wfin, bfin, u, cb);
    final_k<<<dim3(256, 8), 256, 0, stream>>>(x3cl, u, cb, out);
}